// Round 11
// baseline (688.688 us; speedup 1.0000x reference)
//
#include <hip/hip_runtime.h>

typedef unsigned short u16;
typedef unsigned int u32;
typedef u16 u16x8 __attribute__((ext_vector_type(8)));
typedef u16 u16x4 __attribute__((ext_vector_type(4)));
typedef float f32x4 __attribute__((ext_vector_type(4)));
typedef __bf16 bf16x8 __attribute__((ext_vector_type(8)));

#define NHEAD 12
#define NT 261
#define NGL 197
#define CDIM 768
#define KT 14
#define PS_STRIDE 232
#define VT_STRIDE 232

__device__ __forceinline__ float bf2f(u16 u) {
    u32 x = ((u32)u) << 16;
    float f;
    __builtin_memcpy(&f, &x, 4);
    return f;
}
__device__ __forceinline__ u16 f2bf(float f) {
    u32 x;
    __builtin_memcpy(&x, &f, 4);
    x = (x + 0x7fffu + ((x >> 16) & 1u)) >> 16;
    return (u16)x;
}
__device__ __forceinline__ bf16x8 asbf(u16x8 v) {
    bf16x8 r;
    __builtin_memcpy(&r, &v, 16);
    return r;
}

#define GLD_LDS16(g, l) \
    __builtin_amdgcn_global_load_lds((const __attribute__((address_space(1))) void*)(g), \
                                     (__attribute__((address_space(3))) void*)(l), 16, 0, 0)
#define WAITV(n) do { asm volatile("s_waitcnt vmcnt(" #n ")" ::: "memory"); __builtin_amdgcn_sched_barrier(0); } while (0)
#define BARM() asm volatile("s_barrier" ::: "memory")

struct CvArgs {
    const float* in[4];
    u16* out[4];
    int n8[4];
    int K[4];
};

// ---------------- wave-per-row LayerNorm (768 cols) ----------------
__device__ __forceinline__ void ln_row(const float* __restrict__ in, const float* __restrict__ w,
                                       const float* __restrict__ bia, u16* __restrict__ out,
                                       int row, int lane) {
    const float4* r = (const float4*)(in + (size_t)row * CDIM);
    float4 a = r[lane], b4 = r[lane + 64], c4 = r[lane + 128];
    float s  = a.x + a.y + a.z + a.w + b4.x + b4.y + b4.z + b4.w + c4.x + c4.y + c4.z + c4.w;
    float ss = a.x*a.x + a.y*a.y + a.z*a.z + a.w*a.w
             + b4.x*b4.x + b4.y*b4.y + b4.z*b4.z + b4.w*b4.w
             + c4.x*c4.x + c4.y*c4.y + c4.z*c4.z + c4.w*c4.w;
#pragma unroll
    for (int off = 32; off; off >>= 1) {
        s  += __shfl_xor(s, off);
        ss += __shfl_xor(ss, off);
    }
    float mu = s * (1.f / 768.f);
    float var = ss * (1.f / 768.f) - mu * mu;
    float inv = rsqrtf(var + 1e-5f);
    const float4* wp = (const float4*)w;
    const float4* bp = (const float4*)bia;
    u16* o = out + (size_t)row * CDIM;
#pragma unroll
    for (int t = 0; t < 3; ++t) {
        float4 v = (t == 0) ? a : (t == 1) ? b4 : c4;
        float4 ww = wp[lane + t * 64], bb = bp[lane + t * 64];
        u16x4 ov;
        ov[0] = f2bf((v.x - mu) * inv * ww.x + bb.x);
        ov[1] = f2bf((v.y - mu) * inv * ww.y + bb.y);
        ov[2] = f2bf((v.z - mu) * inv * ww.z + bb.z);
        ov[3] = f2bf((v.w - mu) * inv * ww.w + bb.w);
        *(u16x4*)(o + t * 256 + lane * 4) = ov;
    }
}

// y=0: weight fp32 -> bf16 FRAGMENT-ORDERED; y=1: LN1.
// B'[chunk*512 + l*8 + j] = B[ntile*16 + (l&15)][ktile*32 + (l>>4)*8 + j], chunk = ntile*(K/32)+ktile
__global__ __launch_bounds__(256) void pre_k(const float* __restrict__ x, const float* __restrict__ w,
                                             const float* __restrict__ bia, u16* __restrict__ out,
                                             int nrows, CvArgs cv) {
    if (blockIdx.y == 0) {
        int i = blockIdx.x * 256 + threadIdx.x;
        int s0 = cv.n8[0], s1 = s0 + cv.n8[1], s2 = s1 + cv.n8[2], s3 = s2 + cv.n8[3];
        int seg, base;
        if (i < s0)      { seg = 0; base = 0; }
        else if (i < s1) { seg = 1; base = s0; }
        else if (i < s2) { seg = 2; base = s1; }
        else if (i < s3) { seg = 3; base = s2; }
        else return;
        int j = i - base;
        int Kd = cv.K[seg];
        int kd8 = Kd >> 3;
        int n = j / kd8;
        int k8 = j - n * kd8;
        const float* src = cv.in[seg] + (size_t)n * Kd + k8 * 8;
        float4 v0 = *(const float4*)src;
        float4 v1 = *(const float4*)(src + 4);
        u16x8 ov;
        ov[0] = f2bf(v0.x); ov[1] = f2bf(v0.y); ov[2] = f2bf(v0.z); ov[3] = f2bf(v0.w);
        ov[4] = f2bf(v1.x); ov[5] = f2bf(v1.y); ov[6] = f2bf(v1.z); ov[7] = f2bf(v1.w);
        int chunk = (n >> 4) * (Kd >> 5) + (k8 >> 2);
        int dst = chunk * 512 + ((k8 & 3) * 16 + (n & 15)) * 8;
        *(u16x8*)(cv.out[seg] + dst) = ov;
    } else {
        int lane = threadIdx.x & 63, wv = threadIdx.x >> 6;
        int row = blockIdx.x * 4 + wv;
        if (row < nrows) ln_row(x, w, bia, out, row, lane);
    }
}

__global__ __launch_bounds__(256) void ln_w(const float* __restrict__ in, const float* __restrict__ w,
                                            const float* __restrict__ bia, u16* __restrict__ out, int nrows) {
    int lane = threadIdx.x & 63, wv = threadIdx.x >> 6;
    int row = blockIdx.x * 4 + wv;
    if (row < nrows) ln_row(in, w, bia, out, row, lane);
}

// ---------------- 256x256 GEMM: A via LDS (2 slots), B fragment-direct to regs ----------------
// 512 thr = 8 waves (2M x 4N), wave tile 128x64, acc[8][4]. BK=64, nt even.
// Even/odd hand-unrolled bodies with named BqA/BqB (static reg indexing).
// Ledger: 12 loads/step (4 A gld_lds + 8 B reg loads); WAITV(12) at step top drains step t.
// EPI: 0 = plain -> bf16; 2 = +bias +gelu(tanh) -> bf16
template <int EPI>
__global__ __launch_bounds__(512) void gemm9(const u16* __restrict__ A, const u16* __restrict__ Bp,
                                             int M, int N, int K, int nbn,
                                             const float* __restrict__ bias, void* __restrict__ outp) {
    __shared__ __align__(16) u16 smA[2][16384];
    const int tid = threadIdx.x;
    const int nwg = gridDim.x;
    const int q = nwg >> 3, r = nwg & 7;
    const int xcd = blockIdx.x & 7, within = blockIdx.x >> 3;
    const int id2 = (xcd < r ? xcd * (q + 1) : r * (q + 1) + (xcd - r) * q) + within;
    const int bm = id2 / nbn, bn = id2 % nbn;
    const int lane = tid & 63, wv = tid >> 6;
    const int wr = wv >> 2, wc = wv & 3;
    const int l15 = lane & 15, lg = lane >> 4;
    const int arow0 = bm * 256, brow0 = bn * 256;
    const int nt = K >> 6;
    const int kch = K >> 5;

    const int srow = tid >> 3;
    const int sk = ((tid & 7) ^ (srow & 7)) * 8;
    const u16* gA[4];
#pragma unroll
    for (int i = 0; i < 4; ++i) {
        int ar = arow0 + i * 64 + srow;
        if (ar >= M) ar = M - 1;
        gA[i] = A + (size_t)ar * K + sk;
    }
    const u16* gBw = Bp + ((size_t)((brow0 >> 4) + wc * 4)) * kch * 512 + lane * 8;

    auto STAGE_A = [&](int tt) {
        u16* sb = smA[tt & 1];
        const size_t ko = (size_t)tt * 64;
#pragma unroll
        for (int i = 0; i < 4; ++i) GLD_LDS16(gA[i] + ko, sb + i * 4096 + tid * 8);
    };

    f32x4 acc[8][4] = {};
    const int xb = l15 & 7;
    u16x8 BqA[8], BqB[8];

    auto LOADB = [&](u16x8* dst, int tt) {
#pragma unroll
        for (int ni = 0; ni < 4; ++ni)
#pragma unroll
            for (int kk = 0; kk < 2; ++kk)
                dst[ni * 2 + kk] = *(const u16x8*)(gBw + ((size_t)ni * kch + 2 * tt + kk) * 512);
    };
    auto COMPUTE = [&](const u16* sb, const u16x8* Bq) {
#pragma unroll
        for (int mi = 0; mi < 8; ++mi) {
            const u16* arow = sb + (wr * 128 + mi * 16 + l15) * 64;
            bf16x8 a0 = *(const bf16x8*)(arow + ((lg ^ xb) * 8));
            bf16x8 a1 = *(const bf16x8*)(arow + (((4 | lg) ^ xb) * 8));
#pragma unroll
            for (int ni = 0; ni < 4; ++ni) {
                acc[mi][ni] = __builtin_amdgcn_mfma_f32_16x16x32_bf16(a0, asbf(Bq[ni * 2]), acc[mi][ni], 0, 0, 0);
                acc[mi][ni] = __builtin_amdgcn_mfma_f32_16x16x32_bf16(a1, asbf(Bq[ni * 2 + 1]), acc[mi][ni], 0, 0, 0);
            }
        }
    };

    STAGE_A(0);
    LOADB(BqA, 0);
    for (int t = 0; t < nt; t += 2) {
        // even body (slot 0, BqA current)
        STAGE_A(t + 1);
        LOADB(BqB, t + 1);
        WAITV(12);
        BARM();
        COMPUTE(smA[0], BqA);
        if (t + 2 < nt) {
            BARM();                      // release slot 0
            // odd body (slot 1, BqB current), prefetch t+2
            STAGE_A(t + 2);
            LOADB(BqA, t + 2);
            WAITV(12);
            BARM();
            COMPUTE(smA[1], BqB);
            BARM();                      // release slot 1 before next even stage
        } else {
            BARM();                      // release slot 0
            WAITV(0);
            BARM();
            COMPUTE(smA[1], BqB);
        }
    }

#pragma unroll
    for (int mi = 0; mi < 8; ++mi) {
        int row0 = arow0 + wr * 128 + mi * 16 + lg * 4;
#pragma unroll
        for (int ni = 0; ni < 4; ++ni) {
            int col = brow0 + wc * 64 + ni * 16 + l15;
            float bb = (EPI == 0) ? 0.f : bias[col];
#pragma unroll
            for (int rr = 0; rr < 4; ++rr) {
                int row = row0 + rr;
                if (row < M) {
                    float v = acc[mi][ni][rr] + bb;
                    if (EPI == 2) {
                        float z = v + 0.044715f * v * v * v;
                        v = v / (1.f + __expf(-1.5957691216f * z));
                    }
                    ((u16*)outp)[(size_t)row * N + col] = f2bf(v);
                }
            }
        }
    }
}

// ---------------- 128x128 GEMM (narrow-N), A-LDS + B-direct; +bias +resid -> fp32 ----------------
__global__ __launch_bounds__(256) void gemm9n(const u16* __restrict__ A, const u16* __restrict__ Bp,
                                              int M, int N, int K, int nbn,
                                              const float* __restrict__ bias,
                                              const float* __restrict__ resid, void* __restrict__ outp) {
    __shared__ __align__(16) u16 smA[2][8192];
    const int tid = threadIdx.x;
    const int nwg = gridDim.x;
    const int q = nwg >> 3, r = nwg & 7;
    const int xcd = blockIdx.x & 7, within = blockIdx.x >> 3;
    const int id2 = (xcd < r ? xcd * (q + 1) : r * (q + 1) + (xcd - r) * q) + within;
    const int bm = id2 / nbn, bn = id2 % nbn;
    const int lane = tid & 63, wv = tid >> 6;
    const int wr = wv >> 1, wc = wv & 1;
    const int l15 = lane & 15, lg = lane >> 4;
    const int arow0 = bm * 128, brow0 = bn * 128;
    const int nt = K >> 6;
    const int kch = K >> 5;

    const int srow = tid >> 3;
    const int sk = ((tid & 7) ^ (srow & 7)) * 8;
    const u16* gA[4];
#pragma unroll
    for (int i = 0; i < 4; ++i) {
        int ar = arow0 + i * 32 + srow;
        if (ar >= M) ar = M - 1;
        gA[i] = A + (size_t)ar * K + sk;
    }
    const u16* gBw = Bp + ((size_t)((brow0 >> 4) + wc * 4)) * kch * 512 + lane * 8;

    auto STAGE_A = [&](int tt) {
        u16* sb = smA[tt & 1];
        const size_t ko = (size_t)tt * 64;
#pragma unroll
        for (int i = 0; i < 4; ++i) GLD_LDS16(gA[i] + ko, sb + i * 2048 + tid * 8);
    };

    f32x4 acc[4][4] = {};
    const int xb = l15 & 7;
    u16x8 BqA[8], BqB[8];

    auto LOADB = [&](u16x8* dst, int tt) {
#pragma unroll
        for (int ni = 0; ni < 4; ++ni)
#pragma unroll
            for (int kk = 0; kk < 2; ++kk)
                dst[ni * 2 + kk] = *(const u16x8*)(gBw + ((size_t)ni * kch + 2 * tt + kk) * 512);
    };
    auto COMPUTE = [&](const u16* sb, const u16x8* Bq) {
#pragma unroll
        for (int mi = 0; mi < 4; ++mi) {
            const u16* arow = sb + (wr * 64 + mi * 16 + l15) * 64;
            bf16x8 a0 = *(const bf16x8*)(arow + ((lg ^ xb) * 8));
            bf16x8 a1 = *(const bf16x8*)(arow + (((4 | lg) ^ xb) * 8));
#pragma unroll
            for (int ni = 0; ni < 4; ++ni) {
                acc[mi][ni] = __builtin_amdgcn_mfma_f32_16x16x32_bf16(a0, asbf(Bq[ni * 2]), acc[mi][ni], 0, 0, 0);
                acc[mi][ni] = __builtin_amdgcn_mfma_f32_16x16x32_bf16(a1, asbf(Bq[ni * 2 + 1]), acc[mi][ni], 0, 0, 0);
            }
        }
    };

    STAGE_A(0);
    LOADB(BqA, 0);
    for (int t = 0; t < nt; t += 2) {
        STAGE_A(t + 1);
        LOADB(BqB, t + 1);
        WAITV(12);
        BARM();
        COMPUTE(smA[0], BqA);
        if (t + 2 < nt) {
            BARM();
            STAGE_A(t + 2);
            LOADB(BqA, t + 2);
            WAITV(12);
            BARM();
            COMPUTE(smA[1], BqB);
            BARM();
        } else {
            BARM();
            WAITV(0);
            BARM();
            COMPUTE(smA[1], BqB);
        }
    }

#pragma unroll
    for (int mi = 0; mi < 4; ++mi) {
        int row0 = arow0 + wr * 64 + mi * 16 + lg * 4;
#pragma unroll
        for (int ni = 0; ni < 4; ++ni) {
            int col = brow0 + wc * 64 + ni * 16 + l15;
            float bb = bias[col];
#pragma unroll
            for (int rr = 0; rr < 4; ++rr) {
                int row = row0 + rr;
                if (row < M) {
                    float v = acc[mi][ni][rr] + bb + resid[(size_t)row * N + col];
                    ((float*)outp)[(size_t)row * N + col] = v;
                }
            }
        }
    }
}

// ---------------- Fused attention: blocks [0,1536) global MFMA, [1536,2048) neighborhood ------
__global__ __launch_bounds__(256) void attn_fused(const u16* __restrict__ qkv, const float* __restrict__ ps,
                                                  u16* __restrict__ Z) {
    __shared__ __align__(16) u16 lds0[4 * 16 * PS_STRIDE];
    __shared__ __align__(16) u16 Vt[64 * VT_STRIDE];
    const int tid = threadIdx.x;
    const int lane = tid & 63, wv = tid >> 6;

    if (blockIdx.x >= 1536) {
        int idx = blockIdx.x - 1536;
        int b = idx >> 4;
        int m = (idx & 15) * 4 + wv;
        float px = ps[((size_t)b * 64 + m) * 2 + 0] * (1.f / 16.f);
        float py = ps[((size_t)b * 64 + m) * 2 + 1] * (1.f / 16.f);
        int c0 = min(max((int)floorf(px), 0), 13);
        int c1 = min(max((int)ceilf(px), 0), 13);
        int r0 = min(max((int)floorf(py), 0), 13);
        int r1 = min(max((int)ceilf(py), 0), 13);
        int tok[4];
        tok[0] = 1 + r0 * 14 + c0;
        tok[1] = 1 + r1 * 14 + c0;
        tok[2] = 1 + r0 * 14 + c1;
        tok[3] = 1 + r1 * 14 + c1;
        const size_t rowq = ((size_t)b * NT + NGL + m) * 2304;
#pragma unroll 1
        for (int h = 0; h < NHEAD; ++h) {
            float qv = bf2f(qkv[rowq + h * 64 + lane]);
            float a[4];
#pragma unroll
            for (int j = 0; j < 4; ++j) {
                float p = qv * bf2f(qkv[((size_t)b * NT + tok[j]) * 2304 + 768 + h * 64 + lane]);
#pragma unroll
                for (int off = 32; off; off >>= 1) p += __shfl_xor(p, off);
                a[j] = p;
            }
            float mx = fmaxf(fmaxf(a[0], a[1]), fmaxf(a[2], a[3]));
            float e0 = expf(a[0] - mx), e1 = expf(a[1] - mx), e2 = expf(a[2] - mx), e3 = expf(a[3] - mx);
            float inv = 1.f / (e0 + e1 + e2 + e3);
            float v0 = bf2f(qkv[((size_t)b * NT + tok[0]) * 2304 + 1536 + h * 64 + lane]);
            float v1 = bf2f(qkv[((size_t)b * NT + tok[1]) * 2304 + 1536 + h * 64 + lane]);
            float v2 = bf2f(qkv[((size_t)b * NT + tok[2]) * 2304 + 1536 + h * 64 + lane]);
            float v3 = bf2f(qkv[((size_t)b * NT + tok[3]) * 2304 + 1536 + h * 64 + lane]);
            float o = (e0 * v0 + e1 * v1 + e2 * v2 + e3 * v3) * inv;
            Z[((size_t)b * NT + NGL + m) * CDIM + h * 64 + lane] = f2bf(o);
        }
        return;
    }

    const int blk = blockIdx.x;
    const int qt = blk & 3;
    const int bh = blk >> 2;
    const int h = bh % NHEAD, b = bh / NHEAD;
    const int l15 = lane & 15, lg = lane >> 4;
    const u16* base = qkv + (size_t)b * NT * 2304;

    for (int c = tid; c < 224 * 8; c += 256) {
        int row = c >> 3, ch = c & 7;
        u16x8 v = {};
        if (row < NGL) v = *(const u16x8*)(base + (size_t)row * 2304 + 768 + h * 64 + ch * 8);
        int byte = row * 128 + ((ch * 16) ^ ((row & 7) << 4));
        *(u16x8*)((char*)lds0 + byte) = v;
    }
    for (int c = tid; c < 112 * 8; c += 256) {
        int mp = c >> 3, dch = c & 7;
        int m0 = mp * 2;
        u16x8 a0 = {}, a1 = {};
        if (m0 < NGL)     a0 = *(const u16x8*)(base + (size_t)m0 * 2304 + 1536 + h * 64 + dch * 8);
        if (m0 + 1 < NGL) a1 = *(const u16x8*)(base + (size_t)(m0 + 1) * 2304 + 1536 + h * 64 + dch * 8);
#pragma unroll
        for (int j = 0; j < 8; ++j) {
            u32 pk = (u32)a0[j] | ((u32)a1[j] << 16);
            *(u32*)((char*)Vt + (size_t)(dch * 8 + j) * (VT_STRIDE * 2) + m0 * 2) = pk;
        }
    }
    const int q0 = qt * 64 + wv * 16;
    int qrow = q0 + l15; if (qrow > NGL - 1) qrow = NGL - 1;
    bf16x8 aq0 = *(const bf16x8*)(base + (size_t)qrow * 2304 + h * 64 + lg * 8);
    bf16x8 aq1 = *(const bf16x8*)(base + (size_t)qrow * 2304 + h * 64 + 32 + lg * 8);
    __syncthreads();

    f32x4 s[KT];
    const int sw = (l15 & 7) << 4;
#pragma unroll
    for (int t = 0; t < KT; ++t) {
        const char* krow = (const char*)lds0 + (t * 16 + l15) * 128;
        bf16x8 bk0 = *(const bf16x8*)(krow + ((lg * 16) ^ sw));
        bf16x8 bk1 = *(const bf16x8*)(krow + ((64 + lg * 16) ^ sw));
        f32x4 acc = {};
        acc = __builtin_amdgcn_mfma_f32_16x16x32_bf16(aq0, bk0, acc, 0, 0, 0);
        acc = __builtin_amdgcn_mfma_f32_16x16x32_bf16(aq1, bk1, acc, 0, 0, 0);
        s[t] = acc * 0.125f;
    }
    float mx[4] = {-1e30f, -1e30f, -1e30f, -1e30f};
#pragma unroll
    for (int t = 0; t < KT; ++t)
#pragma unroll
        for (int r = 0; r < 4; ++r) mx[r] = fmaxf(mx[r], s[t][r]);
#pragma unroll
    for (int off = 1; off < 16; off <<= 1)
#pragma unroll
        for (int r = 0; r < 4; ++r) mx[r] = fmaxf(mx[r], __shfl_xor(mx[r], off));
    float sum[4] = {};
#pragma unroll
    for (int t = 0; t < KT; ++t) {
        bool valid = (t * 16 + l15) < NGL;
#pragma unroll
        for (int r = 0; r < 4; ++r) {
            float e = valid ? __expf(s[t][r] - mx[r]) : 0.f;
            s[t][r] = e;
            sum[r] += e;
        }
    }
#pragma unroll
    for (int off = 1; off < 16; off <<= 1)
#pragma unroll
        for (int r = 0; r < 4; ++r) sum[r] += __shfl_xor(sum[r], off);
    float inv[4];
#pragma unroll
    for (int r = 0; r < 4; ++r) inv[r] = 1.f / sum[r];

    __syncthreads();
    u16* Pw = lds0 + wv * 16 * PS_STRIDE;
#pragma unroll
    for (int t = 0; t < KT; ++t)
#pragma unroll
        for (int r = 0; r < 4; ++r)
            Pw[(4 * lg + r) * PS_STRIDE + t * 16 + l15] = f2bf(s[t][r] * inv[r]);

    f32x4 o[4] = {};
#pragma unroll
    for (int ks = 0; ks < 7; ++ks) {
        bf16x8 pa = *(const bf16x8*)(Pw + l15 * PS_STRIDE + ks * 32 + lg * 8);
#pragma unroll
        for (int dt = 0; dt < 4; ++dt) {
            bf16x8 bv = *(const bf16x8*)((const char*)Vt + (size_t)(dt * 16 + l15) * (VT_STRIDE * 2) + ks * 64 + lg * 16);
            o[dt] = __builtin_amdgcn_mfma_f32_16x16x32_bf16(pa, bv, o[dt], 0, 0, 0);
        }
    }
#pragma unroll
    for (int dt = 0; dt < 4; ++dt)
#pragma unroll
        for (int r = 0; r < 4; ++r) {
            int q = q0 + 4 * lg + r;
            if (q < NGL) Z[((size_t)b * NT + q) * CDIM + h * 64 + dt * 16 + l15] = f2bf(o[dt][r]);
        }
}

extern "C" void kernel_launch(void* const* d_in, const int* in_sizes, int n_in,
                              void* d_out, int out_size, void* d_ws, size_t ws_size,
                              hipStream_t stream) {
    const float* x      = (const float*)d_in[0];
    const float* ps     = (const float*)d_in[1];
    const float* n1w    = (const float*)d_in[3];
    const float* n1b    = (const float*)d_in[4];
    const float* qkv_w  = (const float*)d_in[5];
    const float* proj_w = (const float*)d_in[6];
    const float* proj_b = (const float*)d_in[7];
    const float* n2w    = (const float*)d_in[8];
    const float* n2b    = (const float*)d_in[9];
    const float* fc1_w  = (const float*)d_in[10];
    const float* fc1_b  = (const float*)d_in[11];
    const float* fc2_w  = (const float*)d_in[12];
    const float* fc2_b  = (const float*)d_in[13];

    char* ws = (char*)d_ws;
    const int M = 32 * NT;  // 8352
    u16* hbuf  = (u16*)ws;                               // 12,828,672 B
    u16* qkvb  = (u16*)(ws + 12828672);                  // 38,486,016 B
    u16* Zb    = (u16*)(ws + 12828672 + 38486016);       // 12,828,672 B
    u16* Gb    = (u16*)(ws + 12828672);                  // 51,314,688 B (aliases qkv+Z, both dead)
    float* x1  = (float*)(ws + 64143360);                // 25,657,344 B
    u16* wq    = (u16*)(ws + 89800704);
    u16* wp    = wq + 2304 * 768;
    u16* w1    = wp + 768 * 768;
    u16* w2    = w1 + 3072 * 768;

    CvArgs cv;
    cv.in[0] = qkv_w;  cv.out[0] = wq; cv.n8[0] = 2304 * 768 / 8; cv.K[0] = 768;
    cv.in[1] = proj_w; cv.out[1] = wp; cv.n8[1] = 768 * 768 / 8;  cv.K[1] = 768;
    cv.in[2] = fc1_w;  cv.out[2] = w1; cv.n8[2] = 3072 * 768 / 8; cv.K[2] = 768;
    cv.in[3] = fc2_w;  cv.out[3] = w2; cv.n8[3] = 768 * 3072 / 8; cv.K[3] = 3072;

    pre_k<<<dim3(3456, 2), 256, 0, stream>>>(x, n1w, n1b, hbuf, M, cv);
    gemm9<0><<<33 * 9, 512, 0, stream>>>(hbuf, wq, M, 2304, 768, 9, nullptr, qkvb);
    attn_fused<<<2048, 256, 0, stream>>>(qkvb, ps, Zb);
    gemm9n<<<66 * 6, 256, 0, stream>>>(Zb, wp, M, 768, 768, 6, proj_b, x, x1);
    ln_w<<<2088, 256, 0, stream>>>(x1, n2w, n2b, hbuf, M);
    gemm9<2><<<33 * 12, 512, 0, stream>>>(hbuf, w1, M, 3072, 768, 12, fc1_b, Gb);
    gemm9n<<<66 * 6, 256, 0, stream>>>(Gb, w2, M, 768, 3072, 6, fc2_b, x1, (float*)d_out);
}

// Round 12
// 343.521 us; speedup vs baseline: 2.0048x; 2.0048x over previous
//
#include <hip/hip_runtime.h>

typedef unsigned short u16;
typedef unsigned int u32;
typedef u16 u16x8 __attribute__((ext_vector_type(8)));
typedef u16 u16x4 __attribute__((ext_vector_type(4)));
typedef float f32x4 __attribute__((ext_vector_type(4)));
typedef __bf16 bf16x8 __attribute__((ext_vector_type(8)));

#define NHEAD 12
#define NT 261
#define NGL 197
#define CDIM 768
#define KT 14
#define PS_STRIDE 232
#define VT_STRIDE 232

__device__ __forceinline__ float bf2f(u16 u) {
    u32 x = ((u32)u) << 16;
    float f;
    __builtin_memcpy(&f, &x, 4);
    return f;
}
__device__ __forceinline__ u16 f2bf(float f) {
    u32 x;
    __builtin_memcpy(&x, &f, 4);
    x = (x + 0x7fffu + ((x >> 16) & 1u)) >> 16;
    return (u16)x;
}

// fragment-ordered address (u16 index) for operand element (row, col) with inner dim Kd.
// chunk = (row/16)*(Kd/32) + col/32 holds a 16x32 tile; lane l of a wave reads
// [l&15 row][(l>>4)*8 col] as one 16B load => pos ((col&31)/8)*16 + (row&15), byte col&7.
__device__ __forceinline__ size_t fragAddr(int row, int col, int Kd) {
    return ((size_t)((row >> 4) * (Kd >> 5) + (col >> 5))) * 512 +
           ((((col >> 3) & 3) * 16 + (row & 15)) * 8 + (col & 7));
}

struct CvArgs {
    const float* in[4];
    u16* out[4];
    int n8[4];
    int K[4];
};

// ---------------- wave-per-row LayerNorm (768 cols) -> fragment-ordered bf16 ----------------
__device__ __forceinline__ void ln_row(const float* __restrict__ in, const float* __restrict__ w,
                                       const float* __restrict__ bia, u16* __restrict__ out,
                                       int row, int lane) {
    const float4* r = (const float4*)(in + (size_t)row * CDIM);
    float4 a = r[lane], b4 = r[lane + 64], c4 = r[lane + 128];
    float s  = a.x + a.y + a.z + a.w + b4.x + b4.y + b4.z + b4.w + c4.x + c4.y + c4.z + c4.w;
    float ss = a.x*a.x + a.y*a.y + a.z*a.z + a.w*a.w
             + b4.x*b4.x + b4.y*b4.y + b4.z*b4.z + b4.w*b4.w
             + c4.x*c4.x + c4.y*c4.y + c4.z*c4.z + c4.w*c4.w;
#pragma unroll
    for (int off = 32; off; off >>= 1) {
        s  += __shfl_xor(s, off);
        ss += __shfl_xor(ss, off);
    }
    float mu = s * (1.f / 768.f);
    float var = ss * (1.f / 768.f) - mu * mu;
    float inv = rsqrtf(var + 1e-5f);
    const float4* wp = (const float4*)w;
    const float4* bp = (const float4*)bia;
#pragma unroll
    for (int t = 0; t < 3; ++t) {
        float4 v = (t == 0) ? a : (t == 1) ? b4 : c4;
        float4 ww = wp[lane + t * 64], bb = bp[lane + t * 64];
        u16x4 ov;
        ov[0] = f2bf((v.x - mu) * inv * ww.x + bb.x);
        ov[1] = f2bf((v.y - mu) * inv * ww.y + bb.y);
        ov[2] = f2bf((v.z - mu) * inv * ww.z + bb.z);
        ov[3] = f2bf((v.w - mu) * inv * ww.w + bb.w);
        int col = t * 256 + lane * 4;
        *(u16x4*)(out + fragAddr(row, col, 768)) = ov;
    }
}

// y=0: weight fp32 -> bf16 fragment-ordered (verified r11); y=1: LN1 -> fragment-ordered
__global__ __launch_bounds__(256) void pre_k(const float* __restrict__ x, const float* __restrict__ w,
                                             const float* __restrict__ bia, u16* __restrict__ out,
                                             int nrows, CvArgs cv) {
    if (blockIdx.y == 0) {
        int i = blockIdx.x * 256 + threadIdx.x;
        int s0 = cv.n8[0], s1 = s0 + cv.n8[1], s2 = s1 + cv.n8[2], s3 = s2 + cv.n8[3];
        int seg, base;
        if (i < s0)      { seg = 0; base = 0; }
        else if (i < s1) { seg = 1; base = s0; }
        else if (i < s2) { seg = 2; base = s1; }
        else if (i < s3) { seg = 3; base = s2; }
        else return;
        int j = i - base;
        int Kd = cv.K[seg];
        int kd8 = Kd >> 3;
        int n = j / kd8;
        int k8 = j - n * kd8;
        const float* src = cv.in[seg] + (size_t)n * Kd + k8 * 8;
        float4 v0 = *(const float4*)src;
        float4 v1 = *(const float4*)(src + 4);
        u16x8 ov;
        ov[0] = f2bf(v0.x); ov[1] = f2bf(v0.y); ov[2] = f2bf(v0.z); ov[3] = f2bf(v0.w);
        ov[4] = f2bf(v1.x); ov[5] = f2bf(v1.y); ov[6] = f2bf(v1.z); ov[7] = f2bf(v1.w);
        *(u16x8*)(cv.out[seg] + fragAddr(n, k8 * 8, Kd)) = ov;
    } else {
        int lane = threadIdx.x & 63, wv = threadIdx.x >> 6;
        int row = blockIdx.x * 4 + wv;
        if (row < nrows) ln_row(x, w, bia, out, row, lane);
    }
}

__global__ __launch_bounds__(256) void ln_w(const float* __restrict__ in, const float* __restrict__ w,
                                            const float* __restrict__ bia, u16* __restrict__ out, int nrows) {
    int lane = threadIdx.x & 63, wv = threadIdx.x >> 6;
    int row = blockIdx.x * 4 + wv;
    if (row < nrows) ln_row(in, w, bia, out, row, lane);
}

// ---------------- LDS-free, barrier-free GEMM: both operands fragment-ordered in L2 -----------
// 256 thr = 4 waves (2x2), wave tile 64x64, acc[4][4] (64 VGPR). BK=64 (2 chunks).
// Per step: 16 coalesced 16B/lane loads (8 A + 8 B) straight to regs, 32 MFMA. No LDS, no
// barriers: waves drift freely; TLP hides L2 latency. mt clamped so no reads past row M-1 tile.
// EPI: 0 = plain -> bf16 row-major; 1 = +bias +resid(fp32) -> fp32 row-major;
//      2 = +bias +gelu(tanh) -> bf16 FRAGMENT-ordered (inner dim = N) for the next GEMM.
template <int EPI>
__global__ __launch_bounds__(256) void gemm10(const u16* __restrict__ Ap, const u16* __restrict__ Bp,
                                              int M, int N, int K, int nbn,
                                              const float* __restrict__ bias,
                                              const float* __restrict__ resid, void* __restrict__ outp) {
    const int tid = threadIdx.x;
    const int nwg = gridDim.x;
    const int q = nwg >> 3, r = nwg & 7;
    const int xcd = blockIdx.x & 7, within = blockIdx.x >> 3;
    const int id2 = (xcd < r ? xcd * (q + 1) : r * (q + 1) + (xcd - r) * q) + within;
    const int bm = id2 / nbn, bn = id2 % nbn;
    const int lane = tid & 63, wv = tid >> 6;
    const int wr = wv >> 1, wc = wv & 1;
    const int l15 = lane & 15, lg = lane >> 4;
    const int nt = K >> 6;
    const int kch = K >> 5;
    const int mtmax = (M - 1) >> 4;

    const u16* aB[4];
    const u16* bB[4];
#pragma unroll
    for (int i = 0; i < 4; ++i) {
        int mt = bm * 8 + wr * 4 + i;
        if (mt > mtmax) mt = mtmax;
        aB[i] = Ap + (size_t)mt * kch * 512 + lane * 8;
        bB[i] = Bp + (size_t)(bn * 8 + wc * 4 + i) * kch * 512 + lane * 8;
    }

    f32x4 acc[4][4] = {};
#pragma unroll 1
    for (int t = 0; t < nt; ++t) {
        bf16x8 af[4][2], bf[4][2];
#pragma unroll
        for (int i = 0; i < 4; ++i) {
            af[i][0] = *(const bf16x8*)(aB[i] + (size_t)(2 * t) * 512);
            af[i][1] = *(const bf16x8*)(aB[i] + (size_t)(2 * t + 1) * 512);
            bf[i][0] = *(const bf16x8*)(bB[i] + (size_t)(2 * t) * 512);
            bf[i][1] = *(const bf16x8*)(bB[i] + (size_t)(2 * t + 1) * 512);
        }
#pragma unroll
        for (int mi = 0; mi < 4; ++mi)
#pragma unroll
            for (int ni = 0; ni < 4; ++ni) {
                acc[mi][ni] = __builtin_amdgcn_mfma_f32_16x16x32_bf16(af[mi][0], bf[ni][0], acc[mi][ni], 0, 0, 0);
                acc[mi][ni] = __builtin_amdgcn_mfma_f32_16x16x32_bf16(af[mi][1], bf[ni][1], acc[mi][ni], 0, 0, 0);
            }
    }

    const int arow0 = bm * 128, bcol0 = bn * 128;
#pragma unroll
    for (int mi = 0; mi < 4; ++mi) {
        int row0 = arow0 + wr * 64 + mi * 16 + lg * 4;
#pragma unroll
        for (int ni = 0; ni < 4; ++ni) {
            int col = bcol0 + wc * 64 + ni * 16 + l15;
            float bb = (EPI == 0) ? 0.f : bias[col];
#pragma unroll
            for (int rr = 0; rr < 4; ++rr) {
                int row = row0 + rr;
                if (row < M) {
                    float v = acc[mi][ni][rr] + bb;
                    if (EPI == 0) {
                        ((u16*)outp)[(size_t)row * N + col] = f2bf(v);
                    } else if (EPI == 1) {
                        v += resid[(size_t)row * N + col];
                        ((float*)outp)[(size_t)row * N + col] = v;
                    } else {
                        float z = v + 0.044715f * v * v * v;
                        v = v / (1.f + __expf(-1.5957691216f * z));
                        ((u16*)outp)[fragAddr(row, col, N)] = f2bf(v);
                    }
                }
            }
        }
    }
}

// ---------------- Fused attention: blocks [0,1536) global MFMA, [1536,2048) neighborhood ------
// Writes Z in FRAGMENT order (inner dim 768) for the proj GEMM.
__global__ __launch_bounds__(256) void attn_fused(const u16* __restrict__ qkv, const float* __restrict__ ps,
                                                  u16* __restrict__ Z) {
    __shared__ __align__(16) u16 lds0[4 * 16 * PS_STRIDE];
    __shared__ __align__(16) u16 Vt[64 * VT_STRIDE];
    const int tid = threadIdx.x;
    const int lane = tid & 63, wv = tid >> 6;

    if (blockIdx.x >= 1536) {
        int idx = blockIdx.x - 1536;
        int b = idx >> 4;
        int m = (idx & 15) * 4 + wv;
        float px = ps[((size_t)b * 64 + m) * 2 + 0] * (1.f / 16.f);
        float py = ps[((size_t)b * 64 + m) * 2 + 1] * (1.f / 16.f);
        int c0 = min(max((int)floorf(px), 0), 13);
        int c1 = min(max((int)ceilf(px), 0), 13);
        int r0 = min(max((int)floorf(py), 0), 13);
        int r1 = min(max((int)ceilf(py), 0), 13);
        int tok[4];
        tok[0] = 1 + r0 * 14 + c0;
        tok[1] = 1 + r1 * 14 + c0;
        tok[2] = 1 + r0 * 14 + c1;
        tok[3] = 1 + r1 * 14 + c1;
        const size_t rowq = ((size_t)b * NT + NGL + m) * 2304;
        const int zrow = b * NT + NGL + m;
#pragma unroll 1
        for (int h = 0; h < NHEAD; ++h) {
            float qv = bf2f(qkv[rowq + h * 64 + lane]);
            float a[4];
#pragma unroll
            for (int j = 0; j < 4; ++j) {
                float p = qv * bf2f(qkv[((size_t)b * NT + tok[j]) * 2304 + 768 + h * 64 + lane]);
#pragma unroll
                for (int off = 32; off; off >>= 1) p += __shfl_xor(p, off);
                a[j] = p;
            }
            float mx = fmaxf(fmaxf(a[0], a[1]), fmaxf(a[2], a[3]));
            float e0 = expf(a[0] - mx), e1 = expf(a[1] - mx), e2 = expf(a[2] - mx), e3 = expf(a[3] - mx);
            float inv = 1.f / (e0 + e1 + e2 + e3);
            float v0 = bf2f(qkv[((size_t)b * NT + tok[0]) * 2304 + 1536 + h * 64 + lane]);
            float v1 = bf2f(qkv[((size_t)b * NT + tok[1]) * 2304 + 1536 + h * 64 + lane]);
            float v2 = bf2f(qkv[((size_t)b * NT + tok[2]) * 2304 + 1536 + h * 64 + lane]);
            float v3 = bf2f(qkv[((size_t)b * NT + tok[3]) * 2304 + 1536 + h * 64 + lane]);
            float o = (e0 * v0 + e1 * v1 + e2 * v2 + e3 * v3) * inv;
            Z[fragAddr(zrow, h * 64 + lane, 768)] = f2bf(o);
        }
        return;
    }

    const int blk = blockIdx.x;
    const int qt = blk & 3;
    const int bh = blk >> 2;
    const int h = bh % NHEAD, b = bh / NHEAD;
    const int l15 = lane & 15, lg = lane >> 4;
    const u16* base = qkv + (size_t)b * NT * 2304;

    for (int c = tid; c < 224 * 8; c += 256) {
        int row = c >> 3, ch = c & 7;
        u16x8 v = {};
        if (row < NGL) v = *(const u16x8*)(base + (size_t)row * 2304 + 768 + h * 64 + ch * 8);
        int byte = row * 128 + ((ch * 16) ^ ((row & 7) << 4));
        *(u16x8*)((char*)lds0 + byte) = v;
    }
    for (int c = tid; c < 112 * 8; c += 256) {
        int mp = c >> 3, dch = c & 7;
        int m0 = mp * 2;
        u16x8 a0 = {}, a1 = {};
        if (m0 < NGL)     a0 = *(const u16x8*)(base + (size_t)m0 * 2304 + 1536 + h * 64 + dch * 8);
        if (m0 + 1 < NGL) a1 = *(const u16x8*)(base + (size_t)(m0 + 1) * 2304 + 1536 + h * 64 + dch * 8);
#pragma unroll
        for (int j = 0; j < 8; ++j) {
            u32 pk = (u32)a0[j] | ((u32)a1[j] << 16);
            *(u32*)((char*)Vt + (size_t)(dch * 8 + j) * (VT_STRIDE * 2) + m0 * 2) = pk;
        }
    }
    const int q0 = qt * 64 + wv * 16;
    int qrow = q0 + l15; if (qrow > NGL - 1) qrow = NGL - 1;
    bf16x8 aq0 = *(const bf16x8*)(base + (size_t)qrow * 2304 + h * 64 + lg * 8);
    bf16x8 aq1 = *(const bf16x8*)(base + (size_t)qrow * 2304 + h * 64 + 32 + lg * 8);
    __syncthreads();

    f32x4 s[KT];
    const int sw = (l15 & 7) << 4;
#pragma unroll
    for (int t = 0; t < KT; ++t) {
        const char* krow = (const char*)lds0 + (t * 16 + l15) * 128;
        bf16x8 bk0 = *(const bf16x8*)(krow + ((lg * 16) ^ sw));
        bf16x8 bk1 = *(const bf16x8*)(krow + ((64 + lg * 16) ^ sw));
        f32x4 acc = {};
        acc = __builtin_amdgcn_mfma_f32_16x16x32_bf16(aq0, bk0, acc, 0, 0, 0);
        acc = __builtin_amdgcn_mfma_f32_16x16x32_bf16(aq1, bk1, acc, 0, 0, 0);
        s[t] = acc * 0.125f;
    }
    float mx[4] = {-1e30f, -1e30f, -1e30f, -1e30f};
#pragma unroll
    for (int t = 0; t < KT; ++t)
#pragma unroll
        for (int r = 0; r < 4; ++r) mx[r] = fmaxf(mx[r], s[t][r]);
#pragma unroll
    for (int off = 1; off < 16; off <<= 1)
#pragma unroll
        for (int r = 0; r < 4; ++r) mx[r] = fmaxf(mx[r], __shfl_xor(mx[r], off));
    float sum[4] = {};
#pragma unroll
    for (int t = 0; t < KT; ++t) {
        bool valid = (t * 16 + l15) < NGL;
#pragma unroll
        for (int r = 0; r < 4; ++r) {
            float e = valid ? __expf(s[t][r] - mx[r]) : 0.f;
            s[t][r] = e;
            sum[r] += e;
        }
    }
#pragma unroll
    for (int off = 1; off < 16; off <<= 1)
#pragma unroll
        for (int r = 0; r < 4; ++r) sum[r] += __shfl_xor(sum[r], off);
    float inv[4];
#pragma unroll
    for (int r = 0; r < 4; ++r) inv[r] = 1.f / sum[r];

    __syncthreads();
    u16* Pw = lds0 + wv * 16 * PS_STRIDE;
#pragma unroll
    for (int t = 0; t < KT; ++t)
#pragma unroll
        for (int r = 0; r < 4; ++r)
            Pw[(4 * lg + r) * PS_STRIDE + t * 16 + l15] = f2bf(s[t][r] * inv[r]);

    f32x4 o[4] = {};
#pragma unroll
    for (int ks = 0; ks < 7; ++ks) {
        bf16x8 pa = *(const bf16x8*)(Pw + l15 * PS_STRIDE + ks * 32 + lg * 8);
#pragma unroll
        for (int dt = 0; dt < 4; ++dt) {
            bf16x8 bv = *(const bf16x8*)((const char*)Vt + (size_t)(dt * 16 + l15) * (VT_STRIDE * 2) + ks * 64 + lg * 16);
            o[dt] = __builtin_amdgcn_mfma_f32_16x16x32_bf16(pa, bv, o[dt], 0, 0, 0);
        }
    }
#pragma unroll
    for (int dt = 0; dt < 4; ++dt)
#pragma unroll
        for (int r = 0; r < 4; ++r) {
            int qq = q0 + 4 * lg + r;
            if (qq < NGL) Z[fragAddr(b * NT + qq, h * 64 + dt * 16 + l15, 768)] = f2bf(o[dt][r]);
        }
}

extern "C" void kernel_launch(void* const* d_in, const int* in_sizes, int n_in,
                              void* d_out, int out_size, void* d_ws, size_t ws_size,
                              hipStream_t stream) {
    const float* x      = (const float*)d_in[0];
    const float* ps     = (const float*)d_in[1];
    const float* n1w    = (const float*)d_in[3];
    const float* n1b    = (const float*)d_in[4];
    const float* qkv_w  = (const float*)d_in[5];
    const float* proj_w = (const float*)d_in[6];
    const float* proj_b = (const float*)d_in[7];
    const float* n2w    = (const float*)d_in[8];
    const float* n2b    = (const float*)d_in[9];
    const float* fc1_w  = (const float*)d_in[10];
    const float* fc1_b  = (const float*)d_in[11];
    const float* fc2_w  = (const float*)d_in[12];
    const float* fc2_b  = (const float*)d_in[13];

    char* ws = (char*)d_ws;
    const int M = 32 * NT;  // 8352; mtmax = 521 -> frag buffers sized 522*K/32 KiB = row-major size
    u16* hbuf  = (u16*)ws;                               // A' frag, 12,828,672 B
    u16* qkvb  = (u16*)(ws + 12828672);                  // row-major, 38,486,016 B
    u16* Zb    = (u16*)(ws + 12828672 + 38486016);       // A' frag, 12,828,672 B
    u16* Gb    = (u16*)(ws + 12828672);                  // A' frag (K=3072), 51,314,688 B (aliases qkv+Z)
    float* x1  = (float*)(ws + 64143360);                // 25,657,344 B
    u16* wq    = (u16*)(ws + 89800704);
    u16* wp    = wq + 2304 * 768;
    u16* w1    = wp + 768 * 768;
    u16* w2    = w1 + 3072 * 768;

    CvArgs cv;
    cv.in[0] = qkv_w;  cv.out[0] = wq; cv.n8[0] = 2304 * 768 / 8; cv.K[0] = 768;
    cv.in[1] = proj_w; cv.out[1] = wp; cv.n8[1] = 768 * 768 / 8;  cv.K[1] = 768;
    cv.in[2] = fc1_w;  cv.out[2] = w1; cv.n8[2] = 3072 * 768 / 8; cv.K[2] = 768;
    cv.in[3] = fc2_w;  cv.out[3] = w2; cv.n8[3] = 768 * 3072 / 8; cv.K[3] = 3072;

    pre_k<<<dim3(3456, 2), 256, 0, stream>>>(x, n1w, n1b, hbuf, M, cv);
    gemm10<0><<<66 * 18, 256, 0, stream>>>(hbuf, wq, M, 2304, 768, 18, nullptr, nullptr, qkvb);
    attn_fused<<<2048, 256, 0, stream>>>(qkvb, ps, Zb);
    gemm10<1><<<66 * 6, 256, 0, stream>>>(Zb, wp, M, 768, 768, 6, proj_b, x, x1);
    ln_w<<<2088, 256, 0, stream>>>(x1, n2w, n2b, hbuf, M);
    gemm10<2><<<66 * 24, 256, 0, stream>>>(hbuf, w1, M, 3072, 768, 24, fc1_b, nullptr, Gb);
    gemm10<1><<<66 * 6, 256, 0, stream>>>(Gb, w2, M, 768, 3072, 6, fc2_b, x1, (float*)d_out);
}

// Round 13
// 316.874 us; speedup vs baseline: 2.1734x; 1.0841x over previous
//
#include <hip/hip_runtime.h>

typedef unsigned short u16;
typedef unsigned int u32;
typedef u16 u16x8 __attribute__((ext_vector_type(8)));
typedef u16 u16x4 __attribute__((ext_vector_type(4)));
typedef float f32x4 __attribute__((ext_vector_type(4)));
typedef __bf16 bf16x8 __attribute__((ext_vector_type(8)));

#define NHEAD 12
#define NT 261
#define NGL 197
#define CDIM 768
#define KT 14
#define PS_STRIDE 232
#define VT_STRIDE 232

__device__ __forceinline__ float bf2f(u16 u) {
    u32 x = ((u32)u) << 16;
    float f;
    __builtin_memcpy(&f, &x, 4);
    return f;
}
__device__ __forceinline__ u16 f2bf(float f) {
    u32 x;
    __builtin_memcpy(&x, &f, 4);
    x = (x + 0x7fffu + ((x >> 16) & 1u)) >> 16;
    return (u16)x;
}

#define GLD_LDS16(g, l) \
    __builtin_amdgcn_global_load_lds((const __attribute__((address_space(1))) void*)(g), \
                                     (__attribute__((address_space(3))) void*)(l), 16, 0, 0)
#define WAITV(n) asm volatile("s_waitcnt vmcnt(" #n ")" ::: "memory")
#define BARM() asm volatile("s_barrier" ::: "memory")

struct CvArgs {
    const float* in[4];
    u16* out[4];
    int n4[4];
};

// ---------------- wave-per-row LayerNorm (768 cols) ----------------
__device__ __forceinline__ void ln_row(const float* __restrict__ in, const float* __restrict__ w,
                                       const float* __restrict__ bia, u16* __restrict__ out,
                                       int row, int lane) {
    const float4* r = (const float4*)(in + (size_t)row * CDIM);
    float4 a = r[lane], b4 = r[lane + 64], c4 = r[lane + 128];
    float s  = a.x + a.y + a.z + a.w + b4.x + b4.y + b4.z + b4.w + c4.x + c4.y + c4.z + c4.w;
    float ss = a.x*a.x + a.y*a.y + a.z*a.z + a.w*a.w
             + b4.x*b4.x + b4.y*b4.y + b4.z*b4.z + b4.w*b4.w
             + c4.x*c4.x + c4.y*c4.y + c4.z*c4.z + c4.w*c4.w;
#pragma unroll
    for (int off = 32; off; off >>= 1) {
        s  += __shfl_xor(s, off);
        ss += __shfl_xor(ss, off);
    }
    float mu = s * (1.f / 768.f);
    float var = ss * (1.f / 768.f) - mu * mu;
    float inv = rsqrtf(var + 1e-5f);
    const float4* wp = (const float4*)w;
    const float4* bp = (const float4*)bia;
    u16* o = out + (size_t)row * CDIM;
#pragma unroll
    for (int t = 0; t < 3; ++t) {
        float4 v = (t == 0) ? a : (t == 1) ? b4 : c4;
        float4 ww = wp[lane + t * 64], bb = bp[lane + t * 64];
        u16x4 ov;
        ov[0] = f2bf((v.x - mu) * inv * ww.x + bb.x);
        ov[1] = f2bf((v.y - mu) * inv * ww.y + bb.y);
        ov[2] = f2bf((v.z - mu) * inv * ww.z + bb.z);
        ov[3] = f2bf((v.w - mu) * inv * ww.w + bb.w);
        *(u16x4*)(o + t * 256 + lane * 4) = ov;
    }
}

// y=0: weight fp32->bf16 conversion (row-major); y=1: LN1 (4 rows/block)
__global__ __launch_bounds__(256) void pre_k(const float* __restrict__ x, const float* __restrict__ w,
                                             const float* __restrict__ bia, u16* __restrict__ out,
                                             int nrows, CvArgs cv) {
    if (blockIdx.y == 0) {
        int i = blockIdx.x * 256 + threadIdx.x;
        int s0 = cv.n4[0], s1 = s0 + cv.n4[1], s2 = s1 + cv.n4[2], s3 = s2 + cv.n4[3];
        const float* in;
        u16* o;
        int base;
        if (i < s0)      { in = cv.in[0]; o = cv.out[0]; base = 0; }
        else if (i < s1) { in = cv.in[1]; o = cv.out[1]; base = s0; }
        else if (i < s2) { in = cv.in[2]; o = cv.out[2]; base = s1; }
        else if (i < s3) { in = cv.in[3]; o = cv.out[3]; base = s2; }
        else return;
        int j = i - base;
        float4 v = ((const float4*)in)[j];
        u16x4 ov;
        ov[0] = f2bf(v.x); ov[1] = f2bf(v.y); ov[2] = f2bf(v.z); ov[3] = f2bf(v.w);
        ((u16x4*)o)[j] = ov;
    } else {
        int lane = threadIdx.x & 63, wv = threadIdx.x >> 6;
        int row = blockIdx.x * 4 + wv;
        if (row < nrows) ln_row(x, w, bia, out, row, lane);
    }
}

__global__ __launch_bounds__(256) void ln_w(const float* __restrict__ in, const float* __restrict__ w,
                                            const float* __restrict__ bia, u16* __restrict__ out, int nrows) {
    int lane = threadIdx.x & 63, wv = threadIdx.x >> 6;
    int row = blockIdx.x * 4 + wv;
    if (row < nrows) ln_row(in, w, bia, out, row, lane);
}

// ---------------- 256x256 MFMA GEMM, 128x64 wave tiles (r8 best-known) ----------------
template <int EPI>
__global__ __launch_bounds__(512, 2) void gemm5(const u16* __restrict__ A, const u16* __restrict__ Bw,
                                                int M, int N, int K, int nbn,
                                                const float* __restrict__ bias,
                                                void* __restrict__ outp) {
    __shared__ __align__(16) u16 sm[2][32768];
    const int tid = threadIdx.x;
    const int nwg = gridDim.x;
    const int q = nwg >> 3, r = nwg & 7;
    const int xcd = blockIdx.x & 7, within = blockIdx.x >> 3;
    const int id2 = (xcd < r ? xcd * (q + 1) : r * (q + 1) + (xcd - r) * q) + within;
    const int bm = id2 / nbn, bn = id2 % nbn;
    const int lane = tid & 63, wv = tid >> 6;
    const int wr = wv >> 2, wc = wv & 3;
    const int l15 = lane & 15, lg = lane >> 4;
    const int arow0 = bm * 256, brow0 = bn * 256;
    const int nt = K >> 6;

    const int srow = tid >> 3;
    const int sk = ((tid & 7) ^ (srow & 7)) * 8;
    const u16* gA[4];
    const u16* gB[4];
#pragma unroll
    for (int i = 0; i < 4; ++i) {
        int ar = arow0 + i * 64 + srow;
        if (ar >= M) ar = M - 1;
        gA[i] = A + (size_t)ar * K + sk;
        gB[i] = Bw + (size_t)(brow0 + i * 64 + srow) * K + sk;
    }

    auto STAGE = [&](int tt) {
        u16* sb = sm[tt & 1];
        const size_t ko = (size_t)tt * 64;
#pragma unroll
        for (int i = 0; i < 4; ++i) GLD_LDS16(gA[i] + ko, sb + i * 4096 + tid * 8);
#pragma unroll
        for (int i = 0; i < 4; ++i) GLD_LDS16(gB[i] + ko, sb + 16384 + i * 4096 + tid * 8);
    };

    f32x4 acc[8][4] = {};
    const int xb = l15 & 7;

    STAGE(0);
    for (int t = 0; t < nt; ++t) {
        if (t + 1 < nt) {
            STAGE(t + 1);
            WAITV(8);
        } else {
            WAITV(0);
        }
        BARM();
        const u16* sb = sm[t & 1];
        bf16x8 bq[4][2];
#pragma unroll
        for (int ni = 0; ni < 4; ++ni)
#pragma unroll
            for (int kk = 0; kk < 2; ++kk)
                bq[ni][kk] = *(const bf16x8*)(sb + 16384 + (wc * 64 + ni * 16 + l15) * 64 + (((kk << 2) | lg) ^ xb) * 8);
#pragma unroll
        for (int mi = 0; mi < 8; ++mi) {
            const u16* arow = sb + (wr * 128 + mi * 16 + l15) * 64;
            bf16x8 a0 = *(const bf16x8*)(arow + ((lg ^ xb) * 8));
            bf16x8 a1 = *(const bf16x8*)(arow + (((4 | lg) ^ xb) * 8));
#pragma unroll
            for (int ni = 0; ni < 4; ++ni) {
                acc[mi][ni] = __builtin_amdgcn_mfma_f32_16x16x32_bf16(a0, bq[ni][0], acc[mi][ni], 0, 0, 0);
                acc[mi][ni] = __builtin_amdgcn_mfma_f32_16x16x32_bf16(a1, bq[ni][1], acc[mi][ni], 0, 0, 0);
            }
        }
        if (t + 2 < nt) BARM();
    }

#pragma unroll
    for (int mi = 0; mi < 8; ++mi) {
        int row0 = arow0 + wr * 128 + mi * 16 + lg * 4;
#pragma unroll
        for (int ni = 0; ni < 4; ++ni) {
            int col = brow0 + wc * 64 + ni * 16 + l15;
            float bb = (EPI == 0) ? 0.f : bias[col];
#pragma unroll
            for (int rr = 0; rr < 4; ++rr) {
                int row = row0 + rr;
                if (row < M) {
                    float v = acc[mi][ni][rr] + bb;
                    if (EPI == 2) {
                        float z = v + 0.044715f * v * v * v;
                        v = v / (1.f + __expf(-1.5957691216f * z));
                    }
                    ((u16*)outp)[(size_t)row * N + col] = f2bf(v);
                }
            }
        }
    }
}

// ---------------- 128x128 pipelined GEMM (narrow-N): +bias +resid(fp32) -> fp32 ----------------
__global__ __launch_bounds__(256, 2) void gemm4n(const u16* __restrict__ A, const u16* __restrict__ Bw,
                                                 int M, int N, int K, int nbn,
                                                 const float* __restrict__ bias,
                                                 const float* __restrict__ resid, void* __restrict__ outp) {
    constexpr int SLOT = 128 * 64 + 8192;
    __shared__ __align__(16) u16 sm[2 * SLOT];
    const int tid = threadIdx.x;
    const int nwg = gridDim.x;
    const int q = nwg >> 3, r = nwg & 7;
    const int xcd = blockIdx.x & 7, within = blockIdx.x >> 3;
    const int id2 = (xcd < r ? xcd * (q + 1) : r * (q + 1) + (xcd - r) * q) + within;
    const int bm = id2 / nbn, bn = id2 % nbn;
    const int lane = tid & 63, wv = tid >> 6;
    const int wr = wv >> 1, wc = wv & 1;
    const int l15 = lane & 15, lg = lane >> 4;
    const int arow0 = bm * 128, brow0 = bn * 128;
    const int nt = K >> 6;

    const int srow = tid >> 3;
    const int sk = ((tid & 7) ^ (srow & 7)) * 8;
    const u16* gA[4];
    const u16* gB[4];
#pragma unroll
    for (int i = 0; i < 4; ++i) {
        int ar = arow0 + i * 32 + srow;
        if (ar >= M) ar = M - 1;
        gA[i] = A + (size_t)ar * K + sk;
        gB[i] = Bw + (size_t)(brow0 + i * 32 + srow) * K + sk;
    }

    auto STAGE = [&](int tt) {
        u16* sb = sm + (tt & 1) * SLOT;
        const size_t ko = (size_t)tt * 64;
#pragma unroll
        for (int i = 0; i < 4; ++i) GLD_LDS16(gA[i] + ko, sb + i * 2048 + tid * 8);
#pragma unroll
        for (int i = 0; i < 4; ++i) GLD_LDS16(gB[i] + ko, sb + 8192 + i * 2048 + tid * 8);
    };

    f32x4 acc[4][4] = {};
    const int xb = l15 & 7;

    STAGE(0);
    for (int t = 0; t < nt; ++t) {
        if (t + 1 < nt) {
            STAGE(t + 1);
            WAITV(8);
        } else {
            WAITV(0);
        }
        BARM();
        const u16* sb = sm + (t & 1) * SLOT;
        bf16x8 af[4][2], bq[4][2];
#pragma unroll
        for (int mi = 0; mi < 4; ++mi)
#pragma unroll
            for (int kk = 0; kk < 2; ++kk)
                af[mi][kk] = *(const bf16x8*)(sb + (wr * 64 + mi * 16 + l15) * 64 + (((kk << 2) | lg) ^ xb) * 8);
#pragma unroll
        for (int ni = 0; ni < 4; ++ni)
#pragma unroll
            for (int kk = 0; kk < 2; ++kk)
                bq[ni][kk] = *(const bf16x8*)(sb + 8192 + (wc * 64 + ni * 16 + l15) * 64 + (((kk << 2) | lg) ^ xb) * 8);
#pragma unroll
        for (int mi = 0; mi < 4; ++mi)
#pragma unroll
            for (int ni = 0; ni < 4; ++ni) {
                acc[mi][ni] = __builtin_amdgcn_mfma_f32_16x16x32_bf16(af[mi][0], bq[ni][0], acc[mi][ni], 0, 0, 0);
                acc[mi][ni] = __builtin_amdgcn_mfma_f32_16x16x32_bf16(af[mi][1], bq[ni][1], acc[mi][ni], 0, 0, 0);
            }
        if (t + 2 < nt) BARM();
    }

#pragma unroll
    for (int mi = 0; mi < 4; ++mi) {
        int row0 = arow0 + wr * 64 + mi * 16 + lg * 4;
#pragma unroll
        for (int ni = 0; ni < 4; ++ni) {
            int col = brow0 + wc * 64 + ni * 16 + l15;
            float bb = bias[col];
#pragma unroll
            for (int rr = 0; rr < 4; ++rr) {
                int row = row0 + rr;
                if (row < M) {
                    float v = acc[mi][ni][rr] + bb + resid[(size_t)row * N + col];
                    ((float*)outp)[(size_t)row * N + col] = v;
                }
            }
        }
    }
}

// ---------------- Fused attention v2 ----------------
// blocks [0,768): global attn, 2 blocks per (b,h); each stages K+Vt ONCE and computes its
// TWO q-tiles (scores for both kept in registers while K is live; K region then reused as P).
// blocks [768,1280): neighborhood attention (as before).
__global__ __launch_bounds__(256) void attn_fused(const u16* __restrict__ qkv, const float* __restrict__ ps,
                                                  u16* __restrict__ Z) {
    __shared__ __align__(16) u16 lds0[4 * 16 * PS_STRIDE];   // K (swizzled), later P
    __shared__ __align__(16) u16 Vt[64 * VT_STRIDE];
    const int tid = threadIdx.x;
    const int lane = tid & 63, wv = tid >> 6;

    if (blockIdx.x >= 768) {
        int idx = blockIdx.x - 768;
        int b = idx >> 4;
        int m = (idx & 15) * 4 + wv;
        float px = ps[((size_t)b * 64 + m) * 2 + 0] * (1.f / 16.f);
        float py = ps[((size_t)b * 64 + m) * 2 + 1] * (1.f / 16.f);
        int c0 = min(max((int)floorf(px), 0), 13);
        int c1 = min(max((int)ceilf(px), 0), 13);
        int r0 = min(max((int)floorf(py), 0), 13);
        int r1 = min(max((int)ceilf(py), 0), 13);
        int tok[4];
        tok[0] = 1 + r0 * 14 + c0;
        tok[1] = 1 + r1 * 14 + c0;
        tok[2] = 1 + r0 * 14 + c1;
        tok[3] = 1 + r1 * 14 + c1;
        const size_t rowq = ((size_t)b * NT + NGL + m) * 2304;
#pragma unroll 1
        for (int h = 0; h < NHEAD; ++h) {
            float qv = bf2f(qkv[rowq + h * 64 + lane]);
            float a[4];
#pragma unroll
            for (int j = 0; j < 4; ++j) {
                float p = qv * bf2f(qkv[((size_t)b * NT + tok[j]) * 2304 + 768 + h * 64 + lane]);
#pragma unroll
                for (int off = 32; off; off >>= 1) p += __shfl_xor(p, off);
                a[j] = p;
            }
            float mx = fmaxf(fmaxf(a[0], a[1]), fmaxf(a[2], a[3]));
            float e0 = expf(a[0] - mx), e1 = expf(a[1] - mx), e2 = expf(a[2] - mx), e3 = expf(a[3] - mx);
            float inv = 1.f / (e0 + e1 + e2 + e3);
            float v0 = bf2f(qkv[((size_t)b * NT + tok[0]) * 2304 + 1536 + h * 64 + lane]);
            float v1 = bf2f(qkv[((size_t)b * NT + tok[1]) * 2304 + 1536 + h * 64 + lane]);
            float v2 = bf2f(qkv[((size_t)b * NT + tok[2]) * 2304 + 1536 + h * 64 + lane]);
            float v3 = bf2f(qkv[((size_t)b * NT + tok[3]) * 2304 + 1536 + h * 64 + lane]);
            float o = (e0 * v0 + e1 * v1 + e2 * v2 + e3 * v3) * inv;
            Z[((size_t)b * NT + NGL + m) * CDIM + h * 64 + lane] = f2bf(o);
        }
        return;
    }

    const int blk = blockIdx.x;
    const int half = blk & 1;
    const int bh = blk >> 1;
    const int h = bh % NHEAD, b = bh / NHEAD;
    const int l15 = lane & 15, lg = lane >> 4;
    const u16* base = qkv + (size_t)b * NT * 2304;

    // stage K (XOR-swizzled rows), zero pad rows >= 197
    for (int c = tid; c < 224 * 8; c += 256) {
        int row = c >> 3, ch = c & 7;
        u16x8 v = {};
        if (row < NGL) v = *(const u16x8*)(base + (size_t)row * 2304 + 768 + h * 64 + ch * 8);
        int byte = row * 128 + ((ch * 16) ^ ((row & 7) << 4));
        *(u16x8*)((char*)lds0 + byte) = v;
    }
    // stage V transposed
    for (int c = tid; c < 112 * 8; c += 256) {
        int mp = c >> 3, dch = c & 7;
        int m0 = mp * 2;
        u16x8 a0 = {}, a1 = {};
        if (m0 < NGL)     a0 = *(const u16x8*)(base + (size_t)m0 * 2304 + 1536 + h * 64 + dch * 8);
        if (m0 + 1 < NGL) a1 = *(const u16x8*)(base + (size_t)(m0 + 1) * 2304 + 1536 + h * 64 + dch * 8);
#pragma unroll
        for (int j = 0; j < 8; ++j) {
            u32 pk = (u32)a0[j] | ((u32)a1[j] << 16);
            *(u32*)((char*)Vt + (size_t)(dch * 8 + j) * (VT_STRIDE * 2) + m0 * 2) = pk;
        }
    }
    // Q fragments for both q-tiles of this half
    const int q0a = half * 128 + wv * 16;
    const int q0b = q0a + 64;
    int qra = min(q0a + l15, NGL - 1);
    int qrb = min(q0b + l15, NGL - 1);
    bf16x8 aqa0 = *(const bf16x8*)(base + (size_t)qra * 2304 + h * 64 + lg * 8);
    bf16x8 aqa1 = *(const bf16x8*)(base + (size_t)qra * 2304 + h * 64 + 32 + lg * 8);
    bf16x8 aqb0 = *(const bf16x8*)(base + (size_t)qrb * 2304 + h * 64 + lg * 8);
    bf16x8 aqb1 = *(const bf16x8*)(base + (size_t)qrb * 2304 + h * 64 + 32 + lg * 8);
    __syncthreads();

    // S for both q-tiles while K is live
    f32x4 sa[KT], sb_[KT];
    const int sw = (l15 & 7) << 4;
#pragma unroll
    for (int t = 0; t < KT; ++t) {
        const char* krow = (const char*)lds0 + (t * 16 + l15) * 128;
        bf16x8 bk0 = *(const bf16x8*)(krow + ((lg * 16) ^ sw));
        bf16x8 bk1 = *(const bf16x8*)(krow + ((64 + lg * 16) ^ sw));
        f32x4 acca = {};
        acca = __builtin_amdgcn_mfma_f32_16x16x32_bf16(aqa0, bk0, acca, 0, 0, 0);
        acca = __builtin_amdgcn_mfma_f32_16x16x32_bf16(aqa1, bk1, acca, 0, 0, 0);
        sa[t] = acca * 0.125f;
        f32x4 accb = {};
        accb = __builtin_amdgcn_mfma_f32_16x16x32_bf16(aqb0, bk0, accb, 0, 0, 0);
        accb = __builtin_amdgcn_mfma_f32_16x16x32_bf16(aqb1, bk1, accb, 0, 0, 0);
        sb_[t] = accb * 0.125f;
    }
    __syncthreads();   // all waves done reading K; lds0 becomes P

    u16* Pw = lds0 + wv * 16 * PS_STRIDE;
#pragma unroll 1
    for (int pass = 0; pass < 2; ++pass) {
        const int q0 = pass ? q0b : q0a;
        f32x4* s = pass ? sb_ : sa;
        // softmax over keys (reduce across 16-lane group and tiles)
        float mx[4] = {-1e30f, -1e30f, -1e30f, -1e30f};
#pragma unroll
        for (int t = 0; t < KT; ++t)
#pragma unroll
            for (int r = 0; r < 4; ++r) mx[r] = fmaxf(mx[r], s[t][r]);
#pragma unroll
        for (int off = 1; off < 16; off <<= 1)
#pragma unroll
            for (int r = 0; r < 4; ++r) mx[r] = fmaxf(mx[r], __shfl_xor(mx[r], off));
        float sum[4] = {};
#pragma unroll
        for (int t = 0; t < KT; ++t) {
            bool valid = (t * 16 + l15) < NGL;
#pragma unroll
            for (int r = 0; r < 4; ++r) {
                float e = valid ? __expf(s[t][r] - mx[r]) : 0.f;
                s[t][r] = e;
                sum[r] += e;
            }
        }
#pragma unroll
        for (int off = 1; off < 16; off <<= 1)
#pragma unroll
            for (int r = 0; r < 4; ++r) sum[r] += __shfl_xor(sum[r], off);
        float inv[4];
#pragma unroll
        for (int r = 0; r < 4; ++r) inv[r] = 1.f / sum[r];

        // write P (own wave strip only -> no cross-wave hazard between passes)
#pragma unroll
        for (int t = 0; t < KT; ++t)
#pragma unroll
            for (int r = 0; r < 4; ++r)
                Pw[(4 * lg + r) * PS_STRIDE + t * 16 + l15] = f2bf(s[t][r] * inv[r]);

        f32x4 o[4] = {};
#pragma unroll
        for (int ks = 0; ks < 7; ++ks) {
            bf16x8 pa = *(const bf16x8*)(Pw + l15 * PS_STRIDE + ks * 32 + lg * 8);
#pragma unroll
            for (int dt = 0; dt < 4; ++dt) {
                bf16x8 bv = *(const bf16x8*)((const char*)Vt + (size_t)(dt * 16 + l15) * (VT_STRIDE * 2) + ks * 64 + lg * 16);
                o[dt] = __builtin_amdgcn_mfma_f32_16x16x32_bf16(pa, bv, o[dt], 0, 0, 0);
            }
        }
#pragma unroll
        for (int dt = 0; dt < 4; ++dt)
#pragma unroll
            for (int r = 0; r < 4; ++r) {
                int qq = q0 + 4 * lg + r;
                if (qq < NGL) Z[((size_t)b * NT + qq) * CDIM + h * 64 + dt * 16 + l15] = f2bf(o[dt][r]);
            }
    }
}

extern "C" void kernel_launch(void* const* d_in, const int* in_sizes, int n_in,
                              void* d_out, int out_size, void* d_ws, size_t ws_size,
                              hipStream_t stream) {
    const float* x      = (const float*)d_in[0];
    const float* ps     = (const float*)d_in[1];
    const float* n1w    = (const float*)d_in[3];
    const float* n1b    = (const float*)d_in[4];
    const float* qkv_w  = (const float*)d_in[5];
    const float* proj_w = (const float*)d_in[6];
    const float* proj_b = (const float*)d_in[7];
    const float* n2w    = (const float*)d_in[8];
    const float* n2b    = (const float*)d_in[9];
    const float* fc1_w  = (const float*)d_in[10];
    const float* fc1_b  = (const float*)d_in[11];
    const float* fc2_w  = (const float*)d_in[12];
    const float* fc2_b  = (const float*)d_in[13];

    char* ws = (char*)d_ws;
    const int M = 32 * NT;  // 8352
    u16* hbuf  = (u16*)ws;                               // 12,828,672 B
    u16* qkvb  = (u16*)(ws + 12828672);                  // 38,486,016 B
    u16* Zb    = (u16*)(ws + 12828672 + 38486016);       // 12,828,672 B
    u16* Gb    = (u16*)(ws + 12828672);                  // 51,314,688 B (aliases qkv+Z, both dead)
    float* x1  = (float*)(ws + 64143360);                // 25,657,344 B
    u16* wq    = (u16*)(ws + 89800704);
    u16* wp    = wq + 2304 * 768;
    u16* w1    = wp + 768 * 768;
    u16* w2    = w1 + 3072 * 768;

    CvArgs cv;
    cv.in[0] = qkv_w;  cv.out[0] = wq; cv.n4[0] = 2304 * 768 / 4;
    cv.in[1] = proj_w; cv.out[1] = wp; cv.n4[1] = 768 * 768 / 4;
    cv.in[2] = fc1_w;  cv.out[2] = w1; cv.n4[2] = 3072 * 768 / 4;
    cv.in[3] = fc2_w;  cv.out[3] = w2; cv.n4[3] = 768 * 3072 / 4;

    pre_k<<<dim3(6912, 2), 256, 0, stream>>>(x, n1w, n1b, hbuf, M, cv);
    gemm5<0><<<33 * 9, 512, 0, stream>>>(hbuf, wq, M, 2304, 768, 9, nullptr, qkvb);
    attn_fused<<<1280, 256, 0, stream>>>(qkvb, ps, Zb);
    gemm4n<<<66 * 6, 256, 0, stream>>>(Zb, wp, M, 768, 768, 6, proj_b, x, x1);
    ln_w<<<2088, 256, 0, stream>>>(x1, n2w, n2b, hbuf, M);
    gemm5<2><<<33 * 12, 512, 0, stream>>>(hbuf, w1, M, 3072, 768, 12, fc1_b, Gb);
    gemm4n<<<66 * 6, 256, 0, stream>>>(Gb, w2, M, 768, 3072, 6, fc2_b, x1, (float*)d_out);
}

// Round 14
// 280.812 us; speedup vs baseline: 2.4525x; 1.1284x over previous
//
#include <hip/hip_runtime.h>

typedef unsigned short u16;
typedef unsigned int u32;
typedef u16 u16x8 __attribute__((ext_vector_type(8)));
typedef u16 u16x4 __attribute__((ext_vector_type(4)));
typedef float f32x4 __attribute__((ext_vector_type(4)));
typedef __bf16 bf16x8 __attribute__((ext_vector_type(8)));

#define NHEAD 12
#define NT 261
#define NGL 197
#define CDIM 768
#define KT 14
#define PS_STRIDE 232
#define VT_STRIDE 232

__device__ __forceinline__ float bf2f(u16 u) {
    u32 x = ((u32)u) << 16;
    float f;
    __builtin_memcpy(&f, &x, 4);
    return f;
}
__device__ __forceinline__ u16 f2bf(float f) {
    u32 x;
    __builtin_memcpy(&x, &f, 4);
    x = (x + 0x7fffu + ((x >> 16) & 1u)) >> 16;
    return (u16)x;
}

#define GLD_LDS16(g, l) \
    __builtin_amdgcn_global_load_lds((const __attribute__((address_space(1))) void*)(g), \
                                     (__attribute__((address_space(3))) void*)(l), 16, 0, 0)
#define WAITV(n) asm volatile("s_waitcnt vmcnt(" #n ")" ::: "memory")
#define BARM() asm volatile("s_barrier" ::: "memory")

struct CvArgs {
    const float* in[4];
    u16* out[4];
    int n4[4];
};

// ---------------- wave-per-row LayerNorm (768 cols) ----------------
__device__ __forceinline__ void ln_row(const float* __restrict__ in, const float* __restrict__ w,
                                       const float* __restrict__ bia, u16* __restrict__ out,
                                       int row, int lane) {
    const float4* r = (const float4*)(in + (size_t)row * CDIM);
    float4 a = r[lane], b4 = r[lane + 64], c4 = r[lane + 128];
    float s  = a.x + a.y + a.z + a.w + b4.x + b4.y + b4.z + b4.w + c4.x + c4.y + c4.z + c4.w;
    float ss = a.x*a.x + a.y*a.y + a.z*a.z + a.w*a.w
             + b4.x*b4.x + b4.y*b4.y + b4.z*b4.z + b4.w*b4.w
             + c4.x*c4.x + c4.y*c4.y + c4.z*c4.z + c4.w*c4.w;
#pragma unroll
    for (int off = 32; off; off >>= 1) {
        s  += __shfl_xor(s, off);
        ss += __shfl_xor(ss, off);
    }
    float mu = s * (1.f / 768.f);
    float var = ss * (1.f / 768.f) - mu * mu;
    float inv = rsqrtf(var + 1e-5f);
    const float4* wp = (const float4*)w;
    const float4* bp = (const float4*)bia;
    u16* o = out + (size_t)row * CDIM;
#pragma unroll
    for (int t = 0; t < 3; ++t) {
        float4 v = (t == 0) ? a : (t == 1) ? b4 : c4;
        float4 ww = wp[lane + t * 64], bb = bp[lane + t * 64];
        u16x4 ov;
        ov[0] = f2bf((v.x - mu) * inv * ww.x + bb.x);
        ov[1] = f2bf((v.y - mu) * inv * ww.y + bb.y);
        ov[2] = f2bf((v.z - mu) * inv * ww.z + bb.z);
        ov[3] = f2bf((v.w - mu) * inv * ww.w + bb.w);
        *(u16x4*)(o + t * 256 + lane * 4) = ov;
    }
}

// y=0: weight fp32->bf16 conversion; y=1: LN1 (4 rows/block)
__global__ __launch_bounds__(256) void pre_k(const float* __restrict__ x, const float* __restrict__ w,
                                             const float* __restrict__ bia, u16* __restrict__ out,
                                             int nrows, CvArgs cv) {
    if (blockIdx.y == 0) {
        int i = blockIdx.x * 256 + threadIdx.x;
        int s0 = cv.n4[0], s1 = s0 + cv.n4[1], s2 = s1 + cv.n4[2], s3 = s2 + cv.n4[3];
        const float* in;
        u16* o;
        int base;
        if (i < s0)      { in = cv.in[0]; o = cv.out[0]; base = 0; }
        else if (i < s1) { in = cv.in[1]; o = cv.out[1]; base = s0; }
        else if (i < s2) { in = cv.in[2]; o = cv.out[2]; base = s1; }
        else if (i < s3) { in = cv.in[3]; o = cv.out[3]; base = s2; }
        else return;
        int j = i - base;
        float4 v = ((const float4*)in)[j];
        u16x4 ov;
        ov[0] = f2bf(v.x); ov[1] = f2bf(v.y); ov[2] = f2bf(v.z); ov[3] = f2bf(v.w);
        ((u16x4*)o)[j] = ov;
    } else {
        int lane = threadIdx.x & 63, wv = threadIdx.x >> 6;
        int row = blockIdx.x * 4 + wv;
        if (row < nrows) ln_row(x, w, bia, out, row, lane);
    }
}

__global__ __launch_bounds__(256) void ln_w(const float* __restrict__ in, const float* __restrict__ w,
                                            const float* __restrict__ bia, u16* __restrict__ out, int nrows) {
    int lane = threadIdx.x & 63, wv = threadIdx.x >> 6;
    int row = blockIdx.x * 4 + wv;
    if (row < nrows) ln_row(in, w, bia, out, row, lane);
}

// ---------------- m97-geometry GEMM: 128x128, BK=32, 32 KB LDS, high occupancy ----------------
// 256 thr = 4 waves (2x2), wave tile 64x64, acc[4][4]. 2 LDS slots x 16 KB.
// Staging: 4 issues/operand/step (issue i = rows i*64+(tid>>2), slot tid&3; linear LDS dest).
// Source slot pre-swizzled: slot ^= (row>>1)&3 (involution; read xor = (l15>>1)&3; 2-way banks).
// Ledger (r5-proven): stage(t+1) at step top, WAITV(8) = stage(t) landed, t+1 in flight.
// __launch_bounds__(256,4) caps VGPR for 4 waves/SIMD; LDS 32 KB -> up to 5 blocks/CU.
// EPI: 0 = plain -> bf16; 1 = +bias +resid(fp32) -> fp32; 2 = +bias +gelu(tanh) -> bf16
template <int EPI>
__global__ __launch_bounds__(256, 4) void gemm11(const u16* __restrict__ A, const u16* __restrict__ Bw,
                                                 int M, int N, int K, int nbn,
                                                 const float* __restrict__ bias,
                                                 const float* __restrict__ resid, void* __restrict__ outp) {
    __shared__ __align__(16) u16 sm[2][8192];   // [slot][A 4096 | B 4096] u16 = 32 KiB
    const int tid = threadIdx.x;
    const int nwg = gridDim.x;
    const int q = nwg >> 3, r = nwg & 7;
    const int xcd = blockIdx.x & 7, within = blockIdx.x >> 3;
    const int id2 = (xcd < r ? xcd * (q + 1) : r * (q + 1) + (xcd - r) * q) + within;
    const int bm = id2 / nbn, bn = id2 % nbn;
    const int lane = tid & 63, wv = tid >> 6;
    const int wr = wv >> 1, wc = wv & 1;
    const int l15 = lane & 15, lg = lane >> 4;
    const int arow0 = bm * 128, brow0 = bn * 128;
    const int nt = K >> 5;                      // K-steps of 32

    // staging coords: issue i covers rows i*32? -> 4096 u16 per operand tile = 128 rows x 32;
    // each issue = 256 lanes x 8 u16 = 2048 u16 = 64 rows. Issue i rows: i*64 + (tid>>2).
    const int srow = tid >> 2;                  // row within issue (0..63)
    const int sslot = tid & 3;
    const int sk = (sslot ^ ((srow >> 1) & 3)) * 8;   // pre-swizzled source col (u16)
    const u16* gA[2];
    const u16* gB[2];
#pragma unroll
    for (int i = 0; i < 2; ++i) {
        int ar = arow0 + i * 64 + srow;
        if (ar >= M) ar = M - 1;
        gA[i] = A + (size_t)ar * K + sk;
        gB[i] = Bw + (size_t)(brow0 + i * 64 + srow) * K + sk;
    }

    auto STAGE = [&](int tt) {
        u16* sb = sm[tt & 1];
        const size_t ko = (size_t)tt * 32;
#pragma unroll
        for (int i = 0; i < 2; ++i) GLD_LDS16(gA[i] + ko, sb + i * 2048 + tid * 8);
#pragma unroll
        for (int i = 0; i < 2; ++i) GLD_LDS16(gB[i] + ko, sb + 4096 + i * 2048 + tid * 8);
    };

    f32x4 acc[4][4] = {};
    const int xb = (l15 >> 1) & 3;              // read-side slot xor

    STAGE(0);
    for (int t = 0; t < nt; ++t) {
        if (t + 1 < nt) {
            STAGE(t + 1);
            WAITV(4);                           // stage(t) landed; stage(t+1)'s 4 in flight
        } else {
            WAITV(0);
        }
        BARM();
        const u16* sb = sm[t & 1];
        bf16x8 af[4], bq[4];
#pragma unroll
        for (int mi = 0; mi < 4; ++mi)
            af[mi] = *(const bf16x8*)(sb + (wr * 64 + mi * 16 + l15) * 32 + ((lg ^ xb) * 8));
#pragma unroll
        for (int ni = 0; ni < 4; ++ni)
            bq[ni] = *(const bf16x8*)(sb + 4096 + (wc * 64 + ni * 16 + l15) * 32 + ((lg ^ xb) * 8));
#pragma unroll
        for (int mi = 0; mi < 4; ++mi)
#pragma unroll
            for (int ni = 0; ni < 4; ++ni)
                acc[mi][ni] = __builtin_amdgcn_mfma_f32_16x16x32_bf16(af[mi], bq[ni], acc[mi][ni], 0, 0, 0);
        if (t + 2 < nt) BARM();                 // release slot (t&1) before stage(t+2) rewrites it
    }

#pragma unroll
    for (int mi = 0; mi < 4; ++mi) {
        int row0 = arow0 + wr * 64 + mi * 16 + lg * 4;
#pragma unroll
        for (int ni = 0; ni < 4; ++ni) {
            int col = brow0 + wc * 64 + ni * 16 + l15;
            float bb = (EPI == 0) ? 0.f : bias[col];
#pragma unroll
            for (int rr = 0; rr < 4; ++rr) {
                int row = row0 + rr;
                if (row < M) {
                    float v = acc[mi][ni][rr] + bb;
                    if (EPI == 2) {
                        float z = v + 0.044715f * v * v * v;
                        v = v / (1.f + __expf(-1.5957691216f * z));
                    }
                    if (EPI == 1) {
                        v += resid[(size_t)row * N + col];
                        ((float*)outp)[(size_t)row * N + col] = v;
                    } else {
                        ((u16*)outp)[(size_t)row * N + col] = f2bf(v);
                    }
                }
            }
        }
    }
}

// ---------------- Fused attention (r8-proven): [0,1536) global MFMA, [1536,2048) neighborhood --
__global__ __launch_bounds__(256) void attn_fused(const u16* __restrict__ qkv, const float* __restrict__ ps,
                                                  u16* __restrict__ Z) {
    __shared__ __align__(16) u16 lds0[4 * 16 * PS_STRIDE];
    __shared__ __align__(16) u16 Vt[64 * VT_STRIDE];
    const int tid = threadIdx.x;
    const int lane = tid & 63, wv = tid >> 6;

    if (blockIdx.x >= 1536) {
        int idx = blockIdx.x - 1536;
        int b = idx >> 4;
        int m = (idx & 15) * 4 + wv;
        float px = ps[((size_t)b * 64 + m) * 2 + 0] * (1.f / 16.f);
        float py = ps[((size_t)b * 64 + m) * 2 + 1] * (1.f / 16.f);
        int c0 = min(max((int)floorf(px), 0), 13);
        int c1 = min(max((int)ceilf(px), 0), 13);
        int r0 = min(max((int)floorf(py), 0), 13);
        int r1 = min(max((int)ceilf(py), 0), 13);
        int tok[4];
        tok[0] = 1 + r0 * 14 + c0;
        tok[1] = 1 + r1 * 14 + c0;
        tok[2] = 1 + r0 * 14 + c1;
        tok[3] = 1 + r1 * 14 + c1;
        const size_t rowq = ((size_t)b * NT + NGL + m) * 2304;
#pragma unroll 1
        for (int h = 0; h < NHEAD; ++h) {
            float qv = bf2f(qkv[rowq + h * 64 + lane]);
            float a[4];
#pragma unroll
            for (int j = 0; j < 4; ++j) {
                float p = qv * bf2f(qkv[((size_t)b * NT + tok[j]) * 2304 + 768 + h * 64 + lane]);
#pragma unroll
                for (int off = 32; off; off >>= 1) p += __shfl_xor(p, off);
                a[j] = p;
            }
            float mx = fmaxf(fmaxf(a[0], a[1]), fmaxf(a[2], a[3]));
            float e0 = expf(a[0] - mx), e1 = expf(a[1] - mx), e2 = expf(a[2] - mx), e3 = expf(a[3] - mx);
            float inv = 1.f / (e0 + e1 + e2 + e3);
            float v0 = bf2f(qkv[((size_t)b * NT + tok[0]) * 2304 + 1536 + h * 64 + lane]);
            float v1 = bf2f(qkv[((size_t)b * NT + tok[1]) * 2304 + 1536 + h * 64 + lane]);
            float v2 = bf2f(qkv[((size_t)b * NT + tok[2]) * 2304 + 1536 + h * 64 + lane]);
            float v3 = bf2f(qkv[((size_t)b * NT + tok[3]) * 2304 + 1536 + h * 64 + lane]);
            float o = (e0 * v0 + e1 * v1 + e2 * v2 + e3 * v3) * inv;
            Z[((size_t)b * NT + NGL + m) * CDIM + h * 64 + lane] = f2bf(o);
        }
        return;
    }

    const int blk = blockIdx.x;
    const int qt = blk & 3;
    const int bh = blk >> 2;
    const int h = bh % NHEAD, b = bh / NHEAD;
    const int l15 = lane & 15, lg = lane >> 4;
    const u16* base = qkv + (size_t)b * NT * 2304;

    for (int c = tid; c < 224 * 8; c += 256) {
        int row = c >> 3, ch = c & 7;
        u16x8 v = {};
        if (row < NGL) v = *(const u16x8*)(base + (size_t)row * 2304 + 768 + h * 64 + ch * 8);
        int byte = row * 128 + ((ch * 16) ^ ((row & 7) << 4));
        *(u16x8*)((char*)lds0 + byte) = v;
    }
    for (int c = tid; c < 112 * 8; c += 256) {
        int mp = c >> 3, dch = c & 7;
        int m0 = mp * 2;
        u16x8 a0 = {}, a1 = {};
        if (m0 < NGL)     a0 = *(const u16x8*)(base + (size_t)m0 * 2304 + 1536 + h * 64 + dch * 8);
        if (m0 + 1 < NGL) a1 = *(const u16x8*)(base + (size_t)(m0 + 1) * 2304 + 1536 + h * 64 + dch * 8);
#pragma unroll
        for (int j = 0; j < 8; ++j) {
            u32 pk = (u32)a0[j] | ((u32)a1[j] << 16);
            *(u32*)((char*)Vt + (size_t)(dch * 8 + j) * (VT_STRIDE * 2) + m0 * 2) = pk;
        }
    }
    const int q0 = qt * 64 + wv * 16;
    int qrow = q0 + l15; if (qrow > NGL - 1) qrow = NGL - 1;
    bf16x8 aq0 = *(const bf16x8*)(base + (size_t)qrow * 2304 + h * 64 + lg * 8);
    bf16x8 aq1 = *(const bf16x8*)(base + (size_t)qrow * 2304 + h * 64 + 32 + lg * 8);
    __syncthreads();

    f32x4 s[KT];
    const int sw = (l15 & 7) << 4;
#pragma unroll
    for (int t = 0; t < KT; ++t) {
        const char* krow = (const char*)lds0 + (t * 16 + l15) * 128;
        bf16x8 bk0 = *(const bf16x8*)(krow + ((lg * 16) ^ sw));
        bf16x8 bk1 = *(const bf16x8*)(krow + ((64 + lg * 16) ^ sw));
        f32x4 acc = {};
        acc = __builtin_amdgcn_mfma_f32_16x16x32_bf16(aq0, bk0, acc, 0, 0, 0);
        acc = __builtin_amdgcn_mfma_f32_16x16x32_bf16(aq1, bk1, acc, 0, 0, 0);
        s[t] = acc * 0.125f;
    }
    float mx[4] = {-1e30f, -1e30f, -1e30f, -1e30f};
#pragma unroll
    for (int t = 0; t < KT; ++t)
#pragma unroll
        for (int r = 0; r < 4; ++r) mx[r] = fmaxf(mx[r], s[t][r]);
#pragma unroll
    for (int off = 1; off < 16; off <<= 1)
#pragma unroll
        for (int r = 0; r < 4; ++r) mx[r] = fmaxf(mx[r], __shfl_xor(mx[r], off));
    float sum[4] = {};
#pragma unroll
    for (int t = 0; t < KT; ++t) {
        bool valid = (t * 16 + l15) < NGL;
#pragma unroll
        for (int r = 0; r < 4; ++r) {
            float e = valid ? __expf(s[t][r] - mx[r]) : 0.f;
            s[t][r] = e;
            sum[r] += e;
        }
    }
#pragma unroll
    for (int off = 1; off < 16; off <<= 1)
#pragma unroll
        for (int r = 0; r < 4; ++r) sum[r] += __shfl_xor(sum[r], off);
    float inv[4];
#pragma unroll
    for (int r = 0; r < 4; ++r) inv[r] = 1.f / sum[r];

    __syncthreads();
    u16* Pw = lds0 + wv * 16 * PS_STRIDE;
#pragma unroll
    for (int t = 0; t < KT; ++t)
#pragma unroll
        for (int r = 0; r < 4; ++r)
            Pw[(4 * lg + r) * PS_STRIDE + t * 16 + l15] = f2bf(s[t][r] * inv[r]);

    f32x4 o[4] = {};
#pragma unroll
    for (int ks = 0; ks < 7; ++ks) {
        bf16x8 pa = *(const bf16x8*)(Pw + l15 * PS_STRIDE + ks * 32 + lg * 8);
#pragma unroll
        for (int dt = 0; dt < 4; ++dt) {
            bf16x8 bv = *(const bf16x8*)((const char*)Vt + (size_t)(dt * 16 + l15) * (VT_STRIDE * 2) + ks * 64 + lg * 16);
            o[dt] = __builtin_amdgcn_mfma_f32_16x16x32_bf16(pa, bv, o[dt], 0, 0, 0);
        }
    }
#pragma unroll
    for (int dt = 0; dt < 4; ++dt)
#pragma unroll
        for (int r = 0; r < 4; ++r) {
            int q = q0 + 4 * lg + r;
            if (q < NGL) Z[((size_t)b * NT + q) * CDIM + h * 64 + dt * 16 + l15] = f2bf(o[dt][r]);
        }
}

extern "C" void kernel_launch(void* const* d_in, const int* in_sizes, int n_in,
                              void* d_out, int out_size, void* d_ws, size_t ws_size,
                              hipStream_t stream) {
    const float* x      = (const float*)d_in[0];
    const float* ps     = (const float*)d_in[1];
    const float* n1w    = (const float*)d_in[3];
    const float* n1b    = (const float*)d_in[4];
    const float* qkv_w  = (const float*)d_in[5];
    const float* proj_w = (const float*)d_in[6];
    const float* proj_b = (const float*)d_in[7];
    const float* n2w    = (const float*)d_in[8];
    const float* n2b    = (const float*)d_in[9];
    const float* fc1_w  = (const float*)d_in[10];
    const float* fc1_b  = (const float*)d_in[11];
    const float* fc2_w  = (const float*)d_in[12];
    const float* fc2_b  = (const float*)d_in[13];

    char* ws = (char*)d_ws;
    const int M = 32 * NT;  // 8352
    u16* hbuf  = (u16*)ws;                               // 12,828,672 B
    u16* qkvb  = (u16*)(ws + 12828672);                  // 38,486,016 B
    u16* Zb    = (u16*)(ws + 12828672 + 38486016);       // 12,828,672 B
    u16* Gb    = (u16*)(ws + 12828672);                  // 51,314,688 B (aliases qkv+Z, both dead)
    float* x1  = (float*)(ws + 64143360);                // 25,657,344 B
    u16* wq    = (u16*)(ws + 89800704);
    u16* wp    = wq + 2304 * 768;
    u16* w1    = wp + 768 * 768;
    u16* w2    = w1 + 3072 * 768;

    CvArgs cv;
    cv.in[0] = qkv_w;  cv.out[0] = wq; cv.n4[0] = 2304 * 768 / 4;
    cv.in[1] = proj_w; cv.out[1] = wp; cv.n4[1] = 768 * 768 / 4;
    cv.in[2] = fc1_w;  cv.out[2] = w1; cv.n4[2] = 3072 * 768 / 4;
    cv.in[3] = fc2_w;  cv.out[3] = w2; cv.n4[3] = 768 * 3072 / 4;

    pre_k<<<dim3(6912, 2), 256, 0, stream>>>(x, n1w, n1b, hbuf, M, cv);
    gemm11<0><<<66 * 18, 256, 0, stream>>>(hbuf, wq, M, 2304, 768, 18, nullptr, nullptr, qkvb);
    attn_fused<<<2048, 256, 0, stream>>>(qkvb, ps, Zb);
    gemm11<1><<<66 * 6, 256, 0, stream>>>(Zb, wp, M, 768, 768, 6, proj_b, x, x1);
    ln_w<<<2088, 256, 0, stream>>>(x1, n2w, n2b, hbuf, M);
    gemm11<2><<<66 * 24, 256, 0, stream>>>(hbuf, w1, M, 3072, 768, 24, fc1_b, nullptr, Gb);
    gemm11<1><<<66 * 6, 256, 0, stream>>>(Gb, w2, M, 768, 3072, 6, fc2_b, x1, (float*)d_out);
}